// Round 1
// baseline (1611.479 us; speedup 1.0000x reference)
//
#include <hip/hip_runtime.h>

#define N_USERS 100000
#define N_ITEMS 50000
#define N_NODES (N_USERS + N_ITEMS)
#define DIM 64
#define NNZ_C 2400000
#define BATCH 16384

// Copy emb into acc and E_cur (float4-vectorized).
__global__ void init_copy(const float* __restrict__ emb,
                          float* __restrict__ acc,
                          float* __restrict__ ecur, int n4) {
    int i = blockIdx.x * blockDim.x + threadIdx.x;
    if (i < n4) {
        float4 v = ((const float4*)emb)[i];
        ((float4*)acc)[i] = v;
        ((float4*)ecur)[i] = v;
    }
}

// One 64-lane wave per edge; lane = dim. E_next[row][lane] += val * E[col][lane].
__global__ void spmm_scatter(const int* __restrict__ rows,
                             const int* __restrict__ cols,
                             const float* __restrict__ vals,
                             const float* __restrict__ E,
                             float* __restrict__ Enext) {
    int t = blockIdx.x * blockDim.x + threadIdx.x;
    int e = t >> 6;
    int lane = t & 63;
    if (e >= NNZ_C) return;
    int eu = __builtin_amdgcn_readfirstlane(e);  // wave-uniform -> scalar loads
    int r = rows[eu];
    int c = cols[eu];
    float v = vals[eu];
    float x = v * E[(size_t)c * DIM + lane];
    atomicAdd(&Enext[(size_t)r * DIM + lane], x);
}

// acc += E (float4-vectorized).
__global__ void acc_add(float* __restrict__ acc, const float* __restrict__ E, int n4) {
    int i = blockIdx.x * blockDim.x + threadIdx.x;
    if (i < n4) {
        float4 a = ((float4*)acc)[i];
        float4 b = ((const float4*)E)[i];
        a.x += b.x; a.y += b.y; a.z += b.z; a.w += b.w;
        ((float4*)acc)[i] = a;
    }
}

// One wave per (U,I) pair: dot over 64 dims, scale by 1/16 (acc/4 on each side).
__global__ void dot_out(const float* __restrict__ acc,
                        const int* __restrict__ U,
                        const int* __restrict__ I,
                        float* __restrict__ out) {
    int t = blockIdx.x * blockDim.x + threadIdx.x;
    int b = t >> 6;
    int lane = t & 63;
    if (b >= BATCH) return;
    int bu = __builtin_amdgcn_readfirstlane(b);
    int u = U[bu];
    int it = I[bu];
    float p = acc[(size_t)u * DIM + lane] * acc[(size_t)(N_USERS + it) * DIM + lane];
    #pragma unroll
    for (int off = 32; off; off >>= 1) p += __shfl_xor(p, off, 64);
    if (lane == 0) out[b] = p * (1.0f / 16.0f);
}

extern "C" void kernel_launch(void* const* d_in, const int* in_sizes, int n_in,
                              void* d_out, int out_size, void* d_ws, size_t ws_size,
                              hipStream_t stream) {
    const float* emb   = (const float*)d_in[0];
    const int*   Arows = (const int*)d_in[1];
    const int*   Acols = (const int*)d_in[2];
    const float* Avals = (const float*)d_in[3];
    const int*   U     = (const int*)d_in[4];
    const int*   I     = (const int*)d_in[5];
    float* out = (float*)d_out;

    size_t ebytes = (size_t)N_NODES * DIM * sizeof(float);
    float* acc = (float*)d_ws;
    float* e0  = (float*)((char*)d_ws + ebytes);
    float* e1  = (float*)((char*)d_ws + 2 * ebytes);

    int n4 = N_NODES * DIM / 4;
    init_copy<<<(n4 + 255) / 256, 256, 0, stream>>>(emb, acc, e0, n4);

    float* cur = e0;
    float* nxt = e1;
    for (int layer = 0; layer < 3; ++layer) {
        hipMemsetAsync(nxt, 0, ebytes, stream);
        long long threads = (long long)NNZ_C * 64;
        spmm_scatter<<<(int)((threads + 255) / 256), 256, 0, stream>>>(
            Arows, Acols, Avals, cur, nxt);
        acc_add<<<(n4 + 255) / 256, 256, 0, stream>>>(acc, nxt, n4);
        float* tmp = cur; cur = nxt; nxt = tmp;
    }

    dot_out<<<(BATCH * 64 + 255) / 256, 256, 0, stream>>>(acc, U, I, out);
}

// Round 2
// 625.563 us; speedup vs baseline: 2.5760x; 2.5760x over previous
//
#include <hip/hip_runtime.h>

#define N_USERS 100000
#define N_ITEMS 50000
#define N_NODES 150000
#define DIM 64
#define NNZ_C 2400000
#define BATCH 16384
#define SCAN_BS 256
#define NBLK ((N_NODES + SCAN_BS - 1) / SCAN_BS)   // 586

// ---- CSR build ------------------------------------------------------------

__global__ void count_rows(const int* __restrict__ rows, int* __restrict__ counts) {
    int e = blockIdx.x * blockDim.x + threadIdx.x;
    if (e < NNZ_C) atomicAdd(&counts[rows[e]], 1);
}

// Per-block inclusive scan of counts -> incl; block totals -> blocksums.
__global__ void scan_blocks(const int* __restrict__ counts,
                            int* __restrict__ incl, int* __restrict__ blocksums) {
    __shared__ int s[SCAN_BS];
    int i = blockIdx.x * SCAN_BS + threadIdx.x;
    int v = (i < N_NODES) ? counts[i] : 0;
    s[threadIdx.x] = v;
    __syncthreads();
    for (int off = 1; off < SCAN_BS; off <<= 1) {
        int t = (threadIdx.x >= off) ? s[threadIdx.x - off] : 0;
        __syncthreads();
        s[threadIdx.x] += t;
        __syncthreads();
    }
    if (i < N_NODES) incl[i] = s[threadIdx.x];
    if (threadIdx.x == SCAN_BS - 1) blocksums[blockIdx.x] = s[SCAN_BS - 1];
}

// Single block: exclusive scan of the 586 block sums.
__global__ void scan_sums(const int* __restrict__ blocksums, int* __restrict__ blockoffs) {
    __shared__ int s[1024];
    int t = threadIdx.x;
    int v = (t < NBLK) ? blocksums[t] : 0;
    s[t] = v;
    __syncthreads();
    for (int off = 1; off < 1024; off <<= 1) {
        int u = (t >= off) ? s[t - off] : 0;
        __syncthreads();
        s[t] += u;
        __syncthreads();
    }
    if (t < NBLK) blockoffs[t] = s[t] - v;   // exclusive
}

__global__ void finalize_rowptr(const int* __restrict__ incl, const int* __restrict__ blockoffs,
                                const int* __restrict__ counts,
                                int* __restrict__ rowptr, int* __restrict__ cursor) {
    int i = blockIdx.x * SCAN_BS + threadIdx.x;
    if (i < N_NODES) {
        int inc = incl[i] + blockoffs[blockIdx.x];
        rowptr[i + 1] = inc;
        cursor[i] = inc - counts[i];   // exclusive start
        if (i == 0) rowptr[0] = 0;
    }
}

// Permute edges into row-grouped order, packing (col, val) into int2.
__global__ void scatter_edges(const int* __restrict__ rows, const int* __restrict__ cols,
                              const float* __restrict__ vals,
                              int* __restrict__ cursor, int2* __restrict__ colval) {
    int e = blockIdx.x * blockDim.x + threadIdx.x;
    if (e >= NNZ_C) return;
    int r = rows[e];
    int pos = atomicAdd(&cursor[r], 1);
    int2 cv;
    cv.x = cols[e];
    cv.y = __float_as_int(vals[e]);
    colval[pos] = cv;
}

// ---- SpMM (gather form): one wave per row, lane = dim --------------------

__global__ void spmm_gather(const int* __restrict__ rowptr, const int2* __restrict__ colval,
                            const float* __restrict__ E, float* __restrict__ Eout) {
    int t = blockIdx.x * blockDim.x + threadIdx.x;
    int row = t >> 6;
    int lane = t & 63;
    if (row >= N_NODES) return;
    int ru = __builtin_amdgcn_readfirstlane(row);
    int start = rowptr[ru];
    int end = rowptr[ru + 1];
    float acc = 0.f;
    int j = start;
    for (; j + 1 < end; j += 2) {
        int2 cv0 = colval[j];
        int2 cv1 = colval[j + 1];
        float x0 = E[(size_t)cv0.x * DIM + lane];
        float x1 = E[(size_t)cv1.x * DIM + lane];
        acc += __int_as_float(cv0.y) * x0;
        acc += __int_as_float(cv1.y) * x1;
    }
    if (j < end) {
        int2 cv = colval[j];
        acc += __int_as_float(cv.y) * E[(size_t)cv.x * DIM + lane];
    }
    Eout[(size_t)row * DIM + lane] = acc;
}

// ---- Batch-row accumulation: accU[b] += E[U[b]], accI[b] += E[U+I[b]] ----

__global__ void batch_acc(const float* __restrict__ E, const int* __restrict__ U,
                          const int* __restrict__ I,
                          float* __restrict__ accU, float* __restrict__ accI) {
    int t = blockIdx.x * blockDim.x + threadIdx.x;
    int b = t >> 6;
    int lane = t & 63;
    if (b >= BATCH) return;
    int bu = __builtin_amdgcn_readfirstlane(b);
    int u = U[bu];
    int it = I[bu];
    accU[(size_t)b * DIM + lane] += E[(size_t)u * DIM + lane];
    accI[(size_t)b * DIM + lane] += E[(size_t)(N_USERS + it) * DIM + lane];
}

// ---- Final dot over 64 dims, scale by 1/16 -------------------------------

__global__ void dot_out(const float* __restrict__ accU, const float* __restrict__ accI,
                        float* __restrict__ out) {
    int t = blockIdx.x * blockDim.x + threadIdx.x;
    int b = t >> 6;
    int lane = t & 63;
    if (b >= BATCH) return;
    float p = accU[(size_t)b * DIM + lane] * accI[(size_t)b * DIM + lane];
    #pragma unroll
    for (int off = 32; off; off >>= 1) p += __shfl_xor(p, off, 64);
    if (lane == 0) out[b] = p * (1.0f / 16.0f);
}

extern "C" void kernel_launch(void* const* d_in, const int* in_sizes, int n_in,
                              void* d_out, int out_size, void* d_ws, size_t ws_size,
                              hipStream_t stream) {
    const float* emb   = (const float*)d_in[0];
    const int*   Arows = (const int*)d_in[1];
    const int*   Acols = (const int*)d_in[2];
    const float* Avals = (const float*)d_in[3];
    const int*   U     = (const int*)d_in[4];
    const int*   I     = (const int*)d_in[5];
    float* out = (float*)d_out;

    char* ws = (char*)d_ws;
    size_t off = 0;
    auto alloc = [&](size_t bytes) {
        char* p = ws + off;
        off += (bytes + 255) & ~(size_t)255;
        return p;
    };
    float* e0       = (float*)alloc((size_t)N_NODES * DIM * 4);   // 38.4 MB
    float* e1       = (float*)alloc((size_t)N_NODES * DIM * 4);   // 38.4 MB
    int2*  colval   = (int2*) alloc((size_t)NNZ_C * 8);           // 19.2 MB
    float* accU     = (float*)alloc((size_t)BATCH * DIM * 4);     // 4.2 MB
    float* accI     = (float*)alloc((size_t)BATCH * DIM * 4);     // 4.2 MB
    int*   rowptr   = (int*)  alloc((size_t)(N_NODES + 1) * 4);
    int*   counts   = (int*)  alloc((size_t)N_NODES * 4);
    int*   cursor   = (int*)  alloc((size_t)N_NODES * 4);
    int*   incl     = (int*)  alloc((size_t)N_NODES * 4);
    int*   blocksums= (int*)  alloc((size_t)NBLK * 4);
    int*   blockoffs= (int*)  alloc((size_t)NBLK * 4);

    hipMemsetAsync(counts, 0, (size_t)N_NODES * 4, stream);
    hipMemsetAsync(accU, 0, (size_t)BATCH * DIM * 4, stream);
    hipMemsetAsync(accI, 0, (size_t)BATCH * DIM * 4, stream);

    // CSR build
    count_rows<<<(NNZ_C + 255) / 256, 256, 0, stream>>>(Arows, counts);
    scan_blocks<<<NBLK, SCAN_BS, 0, stream>>>(counts, incl, blocksums);
    scan_sums<<<1, 1024, 0, stream>>>(blocksums, blockoffs);
    finalize_rowptr<<<NBLK, SCAN_BS, 0, stream>>>(incl, blockoffs, counts, rowptr, cursor);
    scatter_edges<<<(NNZ_C + 255) / 256, 256, 0, stream>>>(Arows, Acols, Avals, cursor, colval);

    int spmm_blocks = (N_NODES * 64 + 255) / 256;   // wave per row
    int bacc_blocks = (BATCH * 64 + 255) / 256;

    // Layer 0 contribution (emb itself)
    batch_acc<<<bacc_blocks, 256, 0, stream>>>(emb, U, I, accU, accI);
    // Layer 1: emb -> e0
    spmm_gather<<<spmm_blocks, 256, 0, stream>>>(rowptr, colval, emb, e0);
    batch_acc<<<bacc_blocks, 256, 0, stream>>>(e0, U, I, accU, accI);
    // Layer 2: e0 -> e1
    spmm_gather<<<spmm_blocks, 256, 0, stream>>>(rowptr, colval, e0, e1);
    batch_acc<<<bacc_blocks, 256, 0, stream>>>(e1, U, I, accU, accI);
    // Layer 3: e1 -> e0
    spmm_gather<<<spmm_blocks, 256, 0, stream>>>(rowptr, colval, e1, e0);
    batch_acc<<<bacc_blocks, 256, 0, stream>>>(e0, U, I, accU, accI);

    dot_out<<<bacc_blocks, 256, 0, stream>>>(accU, accI, out);
}